// Round 1
// baseline (28263.574 us; speedup 1.0000x reference)
//
#include <hip/hip_runtime.h>
#include <cstdint>
#include <cstddef>

#define BLK 256

// ---------------------------------------------------------------- reductions
__device__ __forceinline__ float block_reduce_sum(float v, float* sm) {
#pragma unroll
  for (int off = 32; off > 0; off >>= 1) v += __shfl_down(v, off, 64);
  const int lane = threadIdx.x & 63;
  const int wid  = threadIdx.x >> 6;
  if (lane == 0) sm[wid] = v;
  __syncthreads();
  v = sm[0] + sm[1] + sm[2] + sm[3];
  __syncthreads();
  return v;
}

// ------------------------------------------------------- global average pool
// one block per (b, c) plane of 56x56=3136 floats
__global__ __launch_bounds__(BLK) void gap_x_k(const float* __restrict__ x,
                                               float* __restrict__ y) {
  __shared__ float sm[4];
  const float4* p4 = reinterpret_cast<const float4*>(x + (size_t)blockIdx.x * 3136);
  float s = 0.f;
  for (int i = threadIdx.x; i < 784; i += BLK) {
    float4 v = p4[i];
    s += (v.x + v.y) + (v.z + v.w);
  }
  s = block_reduce_sum(s, sm);
  if (threadIdx.x == 0) y[blockIdx.x] = s * (1.f / 3136.f);
}

// ------------------------------------------------------------ gumbel mask
// 1 block, 128 threads (one per image)
__global__ void mask_k(const float* __restrict__ y, const float* __restrict__ gumbel,
                       const float* __restrict__ nav_w, const float* __restrict__ nbg,
                       const float* __restrict__ nbb, const float* __restrict__ gsw,
                       const float* __restrict__ gsb, float* __restrict__ maskv,
                       float* __restrict__ mask_out) {
  int b = threadIdx.x;
  float d0 = 0.f, d1 = 0.f;
  for (int c = 0; c < 64; ++c) {
    float yv = y[b * 64 + c];
    d0 += yv * nav_w[c];
    d1 += yv * nav_w[64 + c];
  }
  float g0 = fmaxf(d0 * nbg[0] + nbb[0], 0.f);
  float g1 = fmaxf(d1 * nbg[1] + nbb[1], 0.f);
  int vid = b >> 3, s = b & 7;
  // gs_w: [S, j, i]
  float l0 = gsw[s * 4 + 0] * g0 + gsw[s * 4 + 1] * g1 + gsb[s * 2 + 0] + gumbel[(vid * 8 + s) * 2 + 0];
  float l1 = gsw[s * 4 + 2] * g0 + gsw[s * 4 + 3] * g1 + gsb[s * 2 + 1] + gumbel[(vid * 8 + s) * 2 + 1];
  float m = (l1 > l0) ? 1.f : 0.f;   // argmax: ties -> index 0 -> mask 0
  maskv[b] = m;
  mask_out[b] = m;
}

// ------------------------------------------------ avgpool 3x3 s2 p1 (incl pad)
__global__ __launch_bounds__(BLK) void avgpool_k(const float* __restrict__ x,
                                                 float* __restrict__ out) {
  int idx = blockIdx.x * BLK + threadIdx.x;   // 128*64*784 total, exact grid
  int p = idx % 784;
  int bc = idx / 784;
  int h = p / 28, w = p % 28;
  const float* xp = x + (size_t)bc * 3136;
  int h0 = 2 * h - 1, w0 = 2 * w - 1;
  float s = 0.f;
#pragma unroll
  for (int i = 0; i < 3; ++i) {
    int hh = h0 + i;
    if (hh < 0 || hh >= 56) continue;
#pragma unroll
    for (int j = 0; j < 3; ++j) {
      int ww = w0 + j;
      if (ww < 0 || ww >= 56) continue;
      s += xp[hh * 56 + ww];
    }
  }
  out[idx] = s * (1.f / 9.f);
}

// --------------------------------------------------------- direct 3x3 conv
// MODE 0: relu(bn(conv))      MODE 1: bn(conv)+res      MODE 2: relu(bn(conv)+res)
// grid: (chunks, Cout/8, B), 8 ocs per block, pixel-loop per thread
template <int CIN, int STRIDE, int MODE>
__global__ __launch_bounds__(BLK) void conv3x3_k(
    const float* __restrict__ in, const float* __restrict__ wgt,
    const float* __restrict__ gamma, const float* __restrict__ beta,
    const float* __restrict__ res, float* __restrict__ out,
    int Hin, int Win, int Hout, int Wout, int Cout, int pixPerChunk) {
  const int b = blockIdx.z;
  const int oc0 = blockIdx.y * 8;
  const int npix = Hout * Wout;
  int p0 = blockIdx.x * pixPerChunk;
  int p1 = p0 + pixPerChunk;
  if (p1 > npix) p1 = npix;
  const size_t inPlane = (size_t)Hin * Win;
  const float* __restrict__ wb = wgt + (size_t)oc0 * CIN * 9;
  const float* __restrict__ xb = in + (size_t)b * CIN * inPlane;
  float gr[8], br[8];
#pragma unroll
  for (int j = 0; j < 8; ++j) {
    gr[j] = gamma[oc0 + j];
    br[j] = beta[oc0 + j];
  }
  for (int p = p0 + (int)threadIdx.x; p < p1; p += BLK) {
    int h = p / Wout, w = p - h * Wout;
    int hi = h * STRIDE - 1, wi = w * STRIDE - 1;
    float acc[8];
#pragma unroll
    for (int j = 0; j < 8; ++j) acc[j] = 0.f;
    bool interior = (hi >= 0) && (wi >= 0) && (hi + 2 < Hin) && (wi + 2 < Win);
    if (interior) {
      const float* xp = xb + (size_t)hi * Win + wi;
      for (int c = 0; c < CIN; ++c) {
        const float* xr = xp + c * inPlane;
        float x0 = xr[0], x1 = xr[1], x2 = xr[2];
        float x3 = xr[Win], x4 = xr[Win + 1], x5 = xr[Win + 2];
        float x6 = xr[2 * Win], x7 = xr[2 * Win + 1], x8 = xr[2 * Win + 2];
        const float* wc = wb + c * 9;
#pragma unroll
        for (int j = 0; j < 8; ++j) {
          const float* wj = wc + (size_t)j * CIN * 9;
          acc[j] += x0 * wj[0] + x1 * wj[1] + x2 * wj[2]
                  + x3 * wj[3] + x4 * wj[4] + x5 * wj[5]
                  + x6 * wj[6] + x7 * wj[7] + x8 * wj[8];
        }
      }
    } else {
      for (int c = 0; c < CIN; ++c) {
        const float* xr = xb + c * inPlane;
        const float* wc = wb + c * 9;
#pragma unroll
        for (int dh = 0; dh < 3; ++dh) {
          int hh = hi + dh;
          if (hh < 0 || hh >= Hin) continue;
#pragma unroll
          for (int dw = 0; dw < 3; ++dw) {
            int ww = wi + dw;
            if (ww < 0 || ww >= Win) continue;
            float xv = xr[(size_t)hh * Win + ww];
#pragma unroll
            for (int j = 0; j < 8; ++j) acc[j] += xv * wc[(size_t)j * CIN * 9 + dh * 3 + dw];
          }
        }
      }
    }
#pragma unroll
    for (int j = 0; j < 8; ++j) {
      float v = acc[j] * gr[j] + br[j];
      size_t oidx = (size_t)(b * Cout + oc0 + j) * npix + p;
      if constexpr (MODE == 1 || MODE == 2) v += res[oidx];
      if constexpr (MODE == 0 || MODE == 2) v = fmaxf(v, 0.f);
      out[oidx] = v;
    }
  }
}

// ------------------------------- fused x_big: bn(1x1(x)) + mask*bn(3x3(h_f))
__global__ __launch_bounds__(BLK) void conv_xbig_k(
    const float* __restrict__ hf, const float* __restrict__ x,
    const float* __restrict__ w2, const float* __restrict__ g2v, const float* __restrict__ b2v,
    const float* __restrict__ wd, const float* __restrict__ gdv, const float* __restrict__ bdv,
    const float* __restrict__ maskv, float* __restrict__ out, int pixPerChunk) {
  const int b = blockIdx.z;
  const int oc0 = blockIdx.y * 8;
  const float m = maskv[b];
  int p0 = blockIdx.x * pixPerChunk;
  int p1 = p0 + pixPerChunk;
  if (p1 > 3136) p1 = 3136;
  const float* __restrict__ wb = w2 + (size_t)oc0 * 128 * 9;
  const float* __restrict__ hb = hf + (size_t)b * 128 * 3136;
  const float* __restrict__ xb = x + (size_t)b * 64 * 3136;
  float g2r[8], b2r[8], gdr[8], bdr[8];
#pragma unroll
  for (int j = 0; j < 8; ++j) {
    g2r[j] = g2v[oc0 + j]; b2r[j] = b2v[oc0 + j];
    gdr[j] = gdv[oc0 + j]; bdr[j] = bdv[oc0 + j];
  }
  for (int p = p0 + (int)threadIdx.x; p < p1; p += BLK) {
    int h = p / 56, w = p - h * 56;
    int hi = h - 1, wi = w - 1;
    float acc3[8], acc1[8];
#pragma unroll
    for (int j = 0; j < 8; ++j) { acc3[j] = 0.f; acc1[j] = 0.f; }
    bool interior = (h >= 1) && (h <= 54) && (w >= 1) && (w <= 54);
    if (interior) {
      const float* xp = hb + (size_t)hi * 56 + wi;
      for (int c = 0; c < 128; ++c) {
        const float* xr = xp + c * 3136;
        float x0 = xr[0], x1 = xr[1], x2 = xr[2];
        float x3 = xr[56], x4 = xr[57], x5 = xr[58];
        float x6 = xr[112], x7 = xr[113], x8 = xr[114];
        const float* wc = wb + c * 9;
#pragma unroll
        for (int j = 0; j < 8; ++j) {
          const float* wj = wc + (size_t)j * 128 * 9;
          acc3[j] += x0 * wj[0] + x1 * wj[1] + x2 * wj[2]
                   + x3 * wj[3] + x4 * wj[4] + x5 * wj[5]
                   + x6 * wj[6] + x7 * wj[7] + x8 * wj[8];
        }
      }
    } else {
      for (int c = 0; c < 128; ++c) {
        const float* xr = hb + (size_t)c * 3136;
        const float* wc = wb + c * 9;
#pragma unroll
        for (int dh = 0; dh < 3; ++dh) {
          int hh = hi + dh;
          if (hh < 0 || hh >= 56) continue;
#pragma unroll
          for (int dw = 0; dw < 3; ++dw) {
            int ww = wi + dw;
            if (ww < 0 || ww >= 56) continue;
            float xv = xr[hh * 56 + ww];
#pragma unroll
            for (int j = 0; j < 8; ++j) acc3[j] += xv * wc[(size_t)j * 128 * 9 + dh * 3 + dw];
          }
        }
      }
    }
    for (int c = 0; c < 64; ++c) {
      float xv = xb[(size_t)c * 3136 + p];
#pragma unroll
      for (int j = 0; j < 8; ++j) acc1[j] += xv * wd[(oc0 + j) * 64 + c];
    }
#pragma unroll
    for (int j = 0; j < 8; ++j) {
      float v = (acc1[j] * gdr[j] + bdr[j]) + m * (acc3[j] * g2r[j] + b2r[j]);
      out[(size_t)(b * 128 + oc0 + j) * 3136 + p] = v;
    }
  }
}

// --------------------------------------------- base_transform 1x1 conv + bn
__global__ __launch_bounds__(BLK) void conv1x1_bt_k(
    const float* __restrict__ xl, const float* __restrict__ w,
    const float* __restrict__ g, const float* __restrict__ bt, float* __restrict__ out) {
  const int b = blockIdx.z;
  const int oc0 = blockIdx.y * 8;
  const float* __restrict__ xp = xl + (size_t)b * 64 * 784;
  float gr[8], br[8];
#pragma unroll
  for (int j = 0; j < 8; ++j) {
    gr[j] = g[oc0 + j];
    br[j] = bt[oc0 + j];
  }
  for (int p = (int)threadIdx.x; p < 784; p += BLK) {
    float acc[8];
#pragma unroll
    for (int j = 0; j < 8; ++j) acc[j] = 0.f;
    for (int c = 0; c < 64; ++c) {
      float xv = xp[c * 784 + p];
#pragma unroll
      for (int j = 0; j < 8; ++j) acc[j] += xv * w[(oc0 + j) * 64 + c];
    }
#pragma unroll
    for (int j = 0; j < 8; ++j)
      out[(size_t)(b * 128 + oc0 + j) * 784 + p] = acc[j] * gr[j] + br[j];
  }
}

// ------------------------------------- GAP of (x_big + upsampled x_little)
// one block per (b, o); mean56(x_big) + mean28(xl_bt)
__global__ __launch_bounds__(BLK) void gap2_k(const float* __restrict__ xbig,
                                              const float* __restrict__ xlbt,
                                              float* __restrict__ ysum) {
  __shared__ float sm1[4], sm2[4];
  const int bo = blockIdx.x;
  const float4* p4 = reinterpret_cast<const float4*>(xbig + (size_t)bo * 3136);
  float s1 = 0.f;
  for (int i = threadIdx.x; i < 784; i += BLK) {
    float4 v = p4[i];
    s1 += (v.x + v.y) + (v.z + v.w);
  }
  const float4* q4 = reinterpret_cast<const float4*>(xlbt + (size_t)bo * 784);
  float s2 = 0.f;
  for (int i = threadIdx.x; i < 196; i += BLK) {
    float4 v = q4[i];
    s2 += (v.x + v.y) + (v.z + v.w);
  }
  s1 = block_reduce_sum(s1, sm1);
  s2 = block_reduce_sum(s2, sm2);
  if (threadIdx.x == 0) ysum[bo] = s1 * (1.f / 3136.f) + s2 * (1.f / 784.f);
}

// ----------------------------------------------------- SE attention weights
__global__ void att_k(const float* __restrict__ ysum, const float* __restrict__ w1,
                      const float* __restrict__ w2, float* __restrict__ att) {
  int b = blockIdx.x;
  int t = threadIdx.x;  // 128 threads
  __shared__ float hid[8];
  __shared__ float ybuf[128];
  ybuf[t] = ysum[b * 128 + t];
  __syncthreads();
  if (t < 8) {
    float s = 0.f;
    for (int c = 0; c < 128; ++c) s += ybuf[c] * w1[t * 128 + c];
    hid[t] = fmaxf(s, 0.f);
  }
  __syncthreads();
  float s = 0.f;
#pragma unroll
  for (int j = 0; j < 8; ++j) s += hid[j] * w2[t * 8 + j];
  att[b * 128 + t] = 1.f / (1.f + expf(-s));
}

// ------------------------------- SE combine: relu(a*xl_up + (1-a)*x_big), in place
__global__ __launch_bounds__(BLK) void se_k(const float* __restrict__ xlbt,
                                            const float* __restrict__ att,
                                            float* __restrict__ out) {
  int idx = blockIdx.x * BLK + threadIdx.x;  // 51,380,224 total, exact grid
  int p = idx % 3136;
  int bo = idx / 3136;
  int h = p / 56, w = p % 56;
  float a = att[bo];
  float xl = xlbt[(size_t)bo * 784 + (h >> 1) * 28 + (w >> 1)];
  float xb = out[idx];
  out[idx] = fmaxf(a * xl + (1.f - a) * xb, 0.f);
}

// ---------------------------------------------------------------- launcher
extern "C" void kernel_launch(void* const* d_in, const int* in_sizes, int n_in,
                              void* d_out, int out_size, void* d_ws, size_t ws_size,
                              hipStream_t stream) {
  const float* x      = (const float*)d_in[0];
  const float* gumbel = (const float*)d_in[1];
  const float* nav_w  = (const float*)d_in[2];
  const float* nbg    = (const float*)d_in[3];
  const float* nbb    = (const float*)d_in[4];
  const float* gsw    = (const float*)d_in[5];
  const float* gsb    = (const float*)d_in[6];
  const float* ba_w1  = (const float*)d_in[7];
  const float* ba_g1  = (const float*)d_in[8];
  const float* ba_b1  = (const float*)d_in[9];
  const float* ba_w2  = (const float*)d_in[10];
  const float* ba_g2  = (const float*)d_in[11];
  const float* ba_b2  = (const float*)d_in[12];
  const float* bf_wd  = (const float*)d_in[13];
  const float* bf_gd  = (const float*)d_in[14];
  const float* bf_bd  = (const float*)d_in[15];
  const float* bf_w1  = (const float*)d_in[16];
  const float* bf_g1  = (const float*)d_in[17];
  const float* bf_b1  = (const float*)d_in[18];
  const float* bf_w2  = (const float*)d_in[19];
  const float* bf_g2  = (const float*)d_in[20];
  const float* bf_b2  = (const float*)d_in[21];
  const float* bt_w   = (const float*)d_in[22];
  const float* bt_g   = (const float*)d_in[23];
  const float* bt_b   = (const float*)d_in[24];
  const float* att_w1 = (const float*)d_in[25];
  const float* att_w2 = (const float*)d_in[26];
  const float* fu_w1  = (const float*)d_in[27];
  const float* fu_g1  = (const float*)d_in[28];
  const float* fu_b1  = (const float*)d_in[29];
  const float* fu_w2  = (const float*)d_in[30];
  const float* fu_g2  = (const float*)d_in[31];
  const float* fu_b2  = (const float*)d_in[32];

  float* out = (float*)d_out;
  float* ws  = (float*)d_ws;

  const size_t N_OUT = 51380224;  // 128*128*56*56
  float* bufA = ws;               // h_f, then h_fu  (51,380,224 f)
  float* xlbt = bufA + N_OUT;     // [128,128,28,28] (12,845,056 f)
  float* resl = xlbt + 12845056;  // res_l -> x_little (6,422,528 f)
  float* ha   = resl + 6422528;   // h_a              (6,422,528 f)
  float* ygap = ha + 6422528;     // [128,64]
  float* mskv = ygap + 8192;      // [128]
  float* ysum = mskv + 128;       // [128,128]
  float* attb = ysum + 16384;     // [128,128]
  float* mask_out = out + ((size_t)out_size - 128);

  // navigation mask
  gap_x_k<<<8192, BLK, 0, stream>>>(x, ygap);
  mask_k<<<1, 128, 0, stream>>>(ygap, gumbel, nav_w, nbg, nbb, gsw, gsb, mskv, mask_out);

  // ample branch
  avgpool_k<<<25088, BLK, 0, stream>>>(x, resl);
  conv3x3_k<64, 2, 0><<<dim3(1, 8, 128), BLK, 0, stream>>>(
      x, ba_w1, ba_g1, ba_b1, nullptr, ha, 56, 56, 28, 28, 64, 784);
  conv3x3_k<64, 1, 1><<<dim3(1, 8, 128), BLK, 0, stream>>>(
      ha, ba_w2, ba_g2, ba_b2, resl, resl, 28, 28, 28, 28, 64, 784);
  conv1x1_bt_k<<<dim3(1, 16, 128), BLK, 0, stream>>>(resl, bt_w, bt_g, bt_b, xlbt);

  // focal branch
  conv3x3_k<64, 1, 0><<<dim3(4, 16, 128), BLK, 0, stream>>>(
      x, bf_w1, bf_g1, bf_b1, nullptr, bufA, 56, 56, 56, 56, 128, 784);
  conv_xbig_k<<<dim3(4, 16, 128), BLK, 0, stream>>>(
      bufA, x, bf_w2, bf_g2, bf_b2, bf_wd, bf_gd, bf_bd, mskv, out, 784);

  // SE fusion
  gap2_k<<<16384, BLK, 0, stream>>>(out, xlbt, ysum);
  att_k<<<128, 128, 0, stream>>>(ysum, att_w1, att_w2, attb);
  se_k<<<200704, BLK, 0, stream>>>(xlbt, attb, out);

  // fusion residual block
  conv3x3_k<128, 1, 0><<<dim3(4, 16, 128), BLK, 0, stream>>>(
      out, fu_w1, fu_g1, fu_b1, nullptr, bufA, 56, 56, 56, 56, 128, 784);
  conv3x3_k<128, 1, 2><<<dim3(4, 16, 128), BLK, 0, stream>>>(
      bufA, fu_w2, fu_g2, fu_b2, out, out, 56, 56, 56, 56, 128, 784);
}

// Round 2
// 3444.380 us; speedup vs baseline: 8.2057x; 8.2057x over previous
//
#include <hip/hip_runtime.h>
#include <cstdint>
#include <cstddef>

#define BLK 256

typedef __bf16 bf16x8 __attribute__((ext_vector_type(8)));
typedef float  f32x4  __attribute__((ext_vector_type(4)));

// ---------------------------------------------------------------- reductions
__device__ __forceinline__ float block_reduce_sum(float v, float* sm) {
#pragma unroll
  for (int off = 32; off > 0; off >>= 1) v += __shfl_down(v, off, 64);
  const int lane = threadIdx.x & 63;
  const int wid  = threadIdx.x >> 6;
  if (lane == 0) sm[wid] = v;
  __syncthreads();
  v = sm[0] + sm[1] + sm[2] + sm[3];
  __syncthreads();
  return v;
}

// ------------------------------------------------------- global average pool
__global__ __launch_bounds__(BLK) void gap_x_k(const float* __restrict__ x,
                                               float* __restrict__ y) {
  __shared__ float sm[4];
  const float4* p4 = reinterpret_cast<const float4*>(x + (size_t)blockIdx.x * 3136);
  float s = 0.f;
  for (int i = threadIdx.x; i < 784; i += BLK) {
    float4 v = p4[i];
    s += (v.x + v.y) + (v.z + v.w);
  }
  s = block_reduce_sum(s, sm);
  if (threadIdx.x == 0) y[blockIdx.x] = s * (1.f / 3136.f);
}

// ------------------------------------------------------------ gumbel mask
__global__ void mask_k(const float* __restrict__ y, const float* __restrict__ gumbel,
                       const float* __restrict__ nav_w, const float* __restrict__ nbg,
                       const float* __restrict__ nbb, const float* __restrict__ gsw,
                       const float* __restrict__ gsb, float* __restrict__ maskv,
                       float* __restrict__ mask_out) {
  int b = threadIdx.x;
  float d0 = 0.f, d1 = 0.f;
  for (int c = 0; c < 64; ++c) {
    float yv = y[b * 64 + c];
    d0 += yv * nav_w[c];
    d1 += yv * nav_w[64 + c];
  }
  float g0 = fmaxf(d0 * nbg[0] + nbb[0], 0.f);
  float g1 = fmaxf(d1 * nbg[1] + nbb[1], 0.f);
  int vid = b >> 3, s = b & 7;
  float l0 = gsw[s * 4 + 0] * g0 + gsw[s * 4 + 1] * g1 + gsb[s * 2 + 0] + gumbel[(vid * 8 + s) * 2 + 0];
  float l1 = gsw[s * 4 + 2] * g0 + gsw[s * 4 + 3] * g1 + gsb[s * 2 + 1] + gumbel[(vid * 8 + s) * 2 + 1];
  float m = (l1 > l0) ? 1.f : 0.f;
  maskv[b] = m;
  mask_out[b] = m;
}

// ------------------------------------------------ avgpool 3x3 s2 p1
__global__ __launch_bounds__(BLK) void avgpool_k(const float* __restrict__ x,
                                                 float* __restrict__ out) {
  int idx = blockIdx.x * BLK + threadIdx.x;
  int p = idx % 784;
  int bc = idx / 784;
  int h = p / 28, w = p % 28;
  const float* xp = x + (size_t)bc * 3136;
  int h0 = 2 * h - 1, w0 = 2 * w - 1;
  float s = 0.f;
#pragma unroll
  for (int i = 0; i < 3; ++i) {
    int hh = h0 + i;
    if (hh < 0 || hh >= 56) continue;
#pragma unroll
    for (int j = 0; j < 3; ++j) {
      int ww = w0 + j;
      if (ww < 0 || ww >= 56) continue;
      s += xp[hh * 56 + ww];
    }
  }
  out[idx] = s * (1.f / 9.f);
}

// --------------------------------------------------------- fp32 direct conv (ba_w1 only)
template <int CIN, int STRIDE, int MODE>
__global__ __launch_bounds__(BLK) void conv3x3_k(
    const float* __restrict__ in, const float* __restrict__ wgt,
    const float* __restrict__ gamma, const float* __restrict__ beta,
    const float* __restrict__ res, float* __restrict__ out,
    int Hin, int Win, int Hout, int Wout, int Cout, int pixPerChunk) {
  const int b = blockIdx.z;
  const int oc0 = blockIdx.y * 8;
  const int npix = Hout * Wout;
  int p0 = blockIdx.x * pixPerChunk;
  int p1 = p0 + pixPerChunk;
  if (p1 > npix) p1 = npix;
  const size_t inPlane = (size_t)Hin * Win;
  const float* __restrict__ wb = wgt + (size_t)oc0 * CIN * 9;
  const float* __restrict__ xb = in + (size_t)b * CIN * inPlane;
  float gr[8], br[8];
#pragma unroll
  for (int j = 0; j < 8; ++j) {
    gr[j] = gamma[oc0 + j];
    br[j] = beta[oc0 + j];
  }
  for (int p = p0 + (int)threadIdx.x; p < p1; p += BLK) {
    int h = p / Wout, w = p - h * Wout;
    int hi = h * STRIDE - 1, wi = w * STRIDE - 1;
    float acc[8];
#pragma unroll
    for (int j = 0; j < 8; ++j) acc[j] = 0.f;
    bool interior = (hi >= 0) && (wi >= 0) && (hi + 2 < Hin) && (wi + 2 < Win);
    if (interior) {
      const float* xp = xb + (size_t)hi * Win + wi;
      for (int c = 0; c < CIN; ++c) {
        const float* xr = xp + c * inPlane;
        float x0 = xr[0], x1 = xr[1], x2 = xr[2];
        float x3 = xr[Win], x4 = xr[Win + 1], x5 = xr[Win + 2];
        float x6 = xr[2 * Win], x7 = xr[2 * Win + 1], x8 = xr[2 * Win + 2];
        const float* wc = wb + c * 9;
#pragma unroll
        for (int j = 0; j < 8; ++j) {
          const float* wj = wc + (size_t)j * CIN * 9;
          acc[j] += x0 * wj[0] + x1 * wj[1] + x2 * wj[2]
                  + x3 * wj[3] + x4 * wj[4] + x5 * wj[5]
                  + x6 * wj[6] + x7 * wj[7] + x8 * wj[8];
        }
      }
    } else {
      for (int c = 0; c < CIN; ++c) {
        const float* xr = xb + c * inPlane;
        const float* wc = wb + c * 9;
#pragma unroll
        for (int dh = 0; dh < 3; ++dh) {
          int hh = hi + dh;
          if (hh < 0 || hh >= Hin) continue;
#pragma unroll
          for (int dw = 0; dw < 3; ++dw) {
            int ww = wi + dw;
            if (ww < 0 || ww >= Win) continue;
            float xv = xr[(size_t)hh * Win + ww];
#pragma unroll
            for (int j = 0; j < 8; ++j) acc[j] += xv * wc[(size_t)j * CIN * 9 + dh * 3 + dw];
          }
        }
      }
    }
#pragma unroll
    for (int j = 0; j < 8; ++j) {
      float v = acc[j] * gr[j] + br[j];
      size_t oidx = (size_t)(b * Cout + oc0 + j) * npix + p;
      if constexpr (MODE == 1 || MODE == 2) v += res[oidx];
      if constexpr (MODE == 0 || MODE == 2) v = fmaxf(v, 0.f);
      out[oidx] = v;
    }
  }
}

// ------------------------------------------------------- weight prepack (3x3)
// dst fragment order: [q][t][mt][lane][8]: oc=mt*16+(lane&15), c=q*32+(lane>>4)*8+j
__global__ void pack3_k(const float* __restrict__ w, __bf16* __restrict__ dst,
                        int CIN, int MT) {
  int total = (CIN / 32) * 9 * MT * 64;
  int idx = blockIdx.x * BLK + threadIdx.x;
  if (idx >= total) return;
  int lane = idx & 63;
  int g = idx >> 6;
  int mt = g % MT; g /= MT;
  int t = g % 9;  int q = g / 9;
  int oc = mt * 16 + (lane & 15);
  int quad = lane >> 4;
#pragma unroll
  for (int j = 0; j < 8; ++j) {
    int c = q * 32 + quad * 8 + j;
    dst[(size_t)idx * 8 + j] = (__bf16)w[((size_t)oc * CIN + c) * 9 + t];
  }
}

// 1x1 variant
__global__ void pack1_k(const float* __restrict__ w, __bf16* __restrict__ dst,
                        int CIN, int MT) {
  int total = (CIN / 32) * MT * 64;
  int idx = blockIdx.x * BLK + threadIdx.x;
  if (idx >= total) return;
  int lane = idx & 63;
  int g = idx >> 6;
  int mt = g % MT;
  int q = g / MT;
  int oc = mt * 16 + (lane & 15);
  int quad = lane >> 4;
#pragma unroll
  for (int j = 0; j < 8; ++j) {
    int c = q * 32 + quad * 8 + j;
    dst[(size_t)idx * 8 + j] = (__bf16)w[(size_t)oc * CIN + c];
  }
}

// ------------------------------------------------ A-tile staging into LDS
// tile: ROWS x COLS pixels (with halo), 32-channel chunk, bf16, stride 40
template <int W_IMG, int ROWS>
__device__ __forceinline__ void stage_tile(__bf16* lds, const float* __restrict__ in,
                                           int img, int CIN, int c0, int h0) {
  constexpr int COLS = W_IMG + 2;
  constexpr int APIX = ROWS * COLS;
  constexpr int NPIX = W_IMG * W_IMG;
  for (int e = threadIdx.x; e < APIX * 8; e += BLK) {
    int pix = e >> 3, cg = e & 7;
    int r = pix / COLS, cc = pix - r * COLS;
    int gh = h0 - 1 + r, gw = cc - 1;
    bool v = (gh >= 0) && (gh < W_IMG) && (gw >= 0) && (gw < W_IMG);
    const float* sp = in + ((size_t)img * CIN + c0 + cg * 4) * NPIX + gh * W_IMG + gw;
    float f0 = v ? sp[0] : 0.f;
    float f1 = v ? sp[NPIX] : 0.f;
    float f2 = v ? sp[2 * NPIX] : 0.f;
    float f3 = v ? sp[3 * NPIX] : 0.f;
    __bf16 arr[4] = {(__bf16)f0, (__bf16)f1, (__bf16)f2, (__bf16)f3};
    *reinterpret_cast<uint2*>(&lds[pix * 40 + cg * 4]) = *reinterpret_cast<uint2*>(arr);
  }
}

// --------------------------------------------------------- MFMA 3x3 conv
// block: 128 linear pixels x (MTW*2*16) ocs.  4 waves in 2x2 (wm, wn).
// MODE 0: relu(bn)  MODE 1: bn+res  MODE 2: relu(bn+res)
template <int W_IMG, int CIN, int MTW, int MODE>
__global__ __launch_bounds__(BLK, 2) void conv3_mfma(
    const float* __restrict__ in, const __bf16* __restrict__ wp,
    const float* __restrict__ gamma, const float* __restrict__ beta,
    const float* __restrict__ res, float* __restrict__ out) {
  constexpr int ROWS = 128 / W_IMG + 4;
  constexpr int COLS = W_IMG + 2;
  constexpr int NPIX = W_IMG * W_IMG;
  constexpr int NCH  = CIN / 32;
  constexpr int MT_TOT = MTW * 2;
  constexpr int COUT = MT_TOT * 16;
  __shared__ __bf16 lds[ROWS * COLS * 40];

  const int tid = threadIdx.x;
  const int lane = tid & 63, wv = tid >> 6;
  const int wm = wv >> 1, wn = wv & 1;
  const int quad = lane >> 4, li = lane & 15;
  const int img = blockIdx.y;
  const int P0 = blockIdx.x * 128;
  const int h0 = P0 / W_IMG;

  int basee[4]; int pstore[4]; bool pok[4];
#pragma unroll
  for (int nt = 0; nt < 4; ++nt) {
    int p = P0 + wn * 64 + nt * 16 + li;
    bool ok = p < NPIX;
    int p2 = ok ? p : (NPIX - 1);
    int h = p2 / W_IMG, w = p2 - h * W_IMG;
    basee[nt] = ((h - h0) * COLS + w) * 40 + quad * 8;
    pstore[nt] = p2; pok[nt] = ok;
  }

  f32x4 acc[MTW][4];
#pragma unroll
  for (int mt = 0; mt < MTW; ++mt)
#pragma unroll
    for (int nt = 0; nt < 4; ++nt) acc[mt][nt] = (f32x4){0.f, 0.f, 0.f, 0.f};

  const bf16x8* wp8 = reinterpret_cast<const bf16x8*>(wp);

  for (int q = 0; q < NCH; ++q) {
    __syncthreads();
    stage_tile<W_IMG, ROWS>(lds, in, img, CIN, q * 32, h0);
    __syncthreads();
#pragma unroll
    for (int t = 0; t < 9; ++t) {
      const int toff = ((t / 3) * COLS + (t % 3)) * 40;
      bf16x8 wf[MTW];
#pragma unroll
      for (int mt = 0; mt < MTW; ++mt)
        wf[mt] = wp8[(size_t)(((q * 9 + t) * MT_TOT) + wm * MTW + mt) * 64 + lane];
      bf16x8 xf[4];
#pragma unroll
      for (int nt = 0; nt < 4; ++nt)
        xf[nt] = *reinterpret_cast<const bf16x8*>(&lds[basee[nt] + toff]);
#pragma unroll
      for (int mt = 0; mt < MTW; ++mt)
#pragma unroll
        for (int nt = 0; nt < 4; ++nt)
          acc[mt][nt] = __builtin_amdgcn_mfma_f32_16x16x32_bf16(wf[mt], xf[nt], acc[mt][nt], 0, 0, 0);
    }
  }

#pragma unroll
  for (int mt = 0; mt < MTW; ++mt) {
#pragma unroll
    for (int r = 0; r < 4; ++r) {
      int oc = wm * MTW * 16 + mt * 16 + quad * 4 + r;
      float g = gamma[oc], bb = beta[oc];
#pragma unroll
      for (int nt = 0; nt < 4; ++nt) {
        if (!pok[nt]) continue;
        size_t idx = ((size_t)img * COUT + oc) * NPIX + pstore[nt];
        float v = acc[mt][nt][r] * g + bb;
        if constexpr (MODE == 1 || MODE == 2) v += res[idx];
        if constexpr (MODE == 0 || MODE == 2) v = fmaxf(v, 0.f);
        out[idx] = v;
      }
    }
  }
}

// --------------------- fused x_big: bn(1x1(x)) + mask * bn(3x3(h_f)), MFMA
__global__ __launch_bounds__(BLK, 2) void conv_xbig_mfma(
    const float* __restrict__ hf, const float* __restrict__ x,
    const __bf16* __restrict__ wp3, const __bf16* __restrict__ wp1,
    const float* __restrict__ g2v, const float* __restrict__ b2v,
    const float* __restrict__ gdv, const float* __restrict__ bdv,
    const float* __restrict__ maskv, float* __restrict__ out) {
  constexpr int W_IMG = 56, ROWS = 6, COLS = 58, NPIX = 3136;
  __shared__ __bf16 lds[ROWS * COLS * 40];

  const int tid = threadIdx.x;
  const int lane = tid & 63, wv = tid >> 6;
  const int wm = wv >> 1, wn = wv & 1;
  const int quad = lane >> 4, li = lane & 15;
  const int img = blockIdx.y;
  const int P0 = blockIdx.x * 128;
  const int h0 = P0 / W_IMG;
  const float m = maskv[img];

  int basee[4]; int pstore[4]; bool pok[4];
#pragma unroll
  for (int nt = 0; nt < 4; ++nt) {
    int p = P0 + wn * 64 + nt * 16 + li;
    bool ok = p < NPIX;
    int p2 = ok ? p : (NPIX - 1);
    int h = p2 / W_IMG, w = p2 - h * W_IMG;
    basee[nt] = ((h - h0) * COLS + w) * 40 + quad * 8;
    pstore[nt] = p2; pok[nt] = ok;
  }

  f32x4 acc3[4][4], acc1[4][4];
#pragma unroll
  for (int mt = 0; mt < 4; ++mt)
#pragma unroll
    for (int nt = 0; nt < 4; ++nt) {
      acc3[mt][nt] = (f32x4){0.f, 0.f, 0.f, 0.f};
      acc1[mt][nt] = (f32x4){0.f, 0.f, 0.f, 0.f};
    }

  const bf16x8* wp3v = reinterpret_cast<const bf16x8*>(wp3);
  const bf16x8* wp1v = reinterpret_cast<const bf16x8*>(wp1);

  // phase 1: 3x3 over h_f, CIN=128
  for (int q = 0; q < 4; ++q) {
    __syncthreads();
    stage_tile<56, 6>(lds, hf, img, 128, q * 32, h0);
    __syncthreads();
#pragma unroll
    for (int t = 0; t < 9; ++t) {
      const int toff = ((t / 3) * COLS + (t % 3)) * 40;
      bf16x8 wf[4];
#pragma unroll
      for (int mt = 0; mt < 4; ++mt)
        wf[mt] = wp3v[(size_t)(((q * 9 + t) * 8) + wm * 4 + mt) * 64 + lane];
      bf16x8 xf[4];
#pragma unroll
      for (int nt = 0; nt < 4; ++nt)
        xf[nt] = *reinterpret_cast<const bf16x8*>(&lds[basee[nt] + toff]);
#pragma unroll
      for (int mt = 0; mt < 4; ++mt)
#pragma unroll
        for (int nt = 0; nt < 4; ++nt)
          acc3[mt][nt] = __builtin_amdgcn_mfma_f32_16x16x32_bf16(wf[mt], xf[nt], acc3[mt][nt], 0, 0, 0);
    }
  }

  // phase 2: 1x1 over x, CIN=64 (center tap)
  for (int q = 0; q < 2; ++q) {
    __syncthreads();
    stage_tile<56, 6>(lds, x, img, 64, q * 32, h0);
    __syncthreads();
    const int toff = (1 * COLS + 1) * 40;
    bf16x8 wf[4];
#pragma unroll
    for (int mt = 0; mt < 4; ++mt)
      wf[mt] = wp1v[(size_t)((q * 8) + wm * 4 + mt) * 64 + lane];
    bf16x8 xf[4];
#pragma unroll
    for (int nt = 0; nt < 4; ++nt)
      xf[nt] = *reinterpret_cast<const bf16x8*>(&lds[basee[nt] + toff]);
#pragma unroll
    for (int mt = 0; mt < 4; ++mt)
#pragma unroll
      for (int nt = 0; nt < 4; ++nt)
        acc1[mt][nt] = __builtin_amdgcn_mfma_f32_16x16x32_bf16(wf[mt], xf[nt], acc1[mt][nt], 0, 0, 0);
  }

#pragma unroll
  for (int mt = 0; mt < 4; ++mt) {
#pragma unroll
    for (int r = 0; r < 4; ++r) {
      int oc = wm * 64 + mt * 16 + quad * 4 + r;
      float g2 = g2v[oc], b2 = b2v[oc], gd = gdv[oc], bd = bdv[oc];
#pragma unroll
      for (int nt = 0; nt < 4; ++nt) {
        if (!pok[nt]) continue;
        size_t idx = ((size_t)img * 128 + oc) * NPIX + pstore[nt];
        float v = (acc1[mt][nt][r] * gd + bd) + m * (acc3[mt][nt][r] * g2 + b2);
        out[idx] = v;
      }
    }
  }
}

// --------------------------------------------- base_transform 1x1 conv + bn
__global__ __launch_bounds__(BLK) void conv1x1_bt_k(
    const float* __restrict__ xl, const float* __restrict__ w,
    const float* __restrict__ g, const float* __restrict__ bt, float* __restrict__ out) {
  const int b = blockIdx.z;
  const int oc0 = blockIdx.y * 8;
  const float* __restrict__ xp = xl + (size_t)b * 64 * 784;
  float gr[8], br[8];
#pragma unroll
  for (int j = 0; j < 8; ++j) {
    gr[j] = g[oc0 + j];
    br[j] = bt[oc0 + j];
  }
  for (int p = (int)threadIdx.x; p < 784; p += BLK) {
    float acc[8];
#pragma unroll
    for (int j = 0; j < 8; ++j) acc[j] = 0.f;
    for (int c = 0; c < 64; ++c) {
      float xv = xp[c * 784 + p];
#pragma unroll
      for (int j = 0; j < 8; ++j) acc[j] += xv * w[(oc0 + j) * 64 + c];
    }
#pragma unroll
    for (int j = 0; j < 8; ++j)
      out[(size_t)(b * 128 + oc0 + j) * 784 + p] = acc[j] * gr[j] + br[j];
  }
}

// ------------------------------------- GAP of (x_big + upsampled x_little)
__global__ __launch_bounds__(BLK) void gap2_k(const float* __restrict__ xbig,
                                              const float* __restrict__ xlbt,
                                              float* __restrict__ ysum) {
  __shared__ float sm1[4], sm2[4];
  const int bo = blockIdx.x;
  const float4* p4 = reinterpret_cast<const float4*>(xbig + (size_t)bo * 3136);
  float s1 = 0.f;
  for (int i = threadIdx.x; i < 784; i += BLK) {
    float4 v = p4[i];
    s1 += (v.x + v.y) + (v.z + v.w);
  }
  const float4* q4 = reinterpret_cast<const float4*>(xlbt + (size_t)bo * 784);
  float s2 = 0.f;
  for (int i = threadIdx.x; i < 196; i += BLK) {
    float4 v = q4[i];
    s2 += (v.x + v.y) + (v.z + v.w);
  }
  s1 = block_reduce_sum(s1, sm1);
  s2 = block_reduce_sum(s2, sm2);
  if (threadIdx.x == 0) ysum[bo] = s1 * (1.f / 3136.f) + s2 * (1.f / 784.f);
}

// ----------------------------------------------------- SE attention weights
__global__ void att_k(const float* __restrict__ ysum, const float* __restrict__ w1,
                      const float* __restrict__ w2, float* __restrict__ att) {
  int b = blockIdx.x;
  int t = threadIdx.x;
  __shared__ float hid[8];
  __shared__ float ybuf[128];
  ybuf[t] = ysum[b * 128 + t];
  __syncthreads();
  if (t < 8) {
    float s = 0.f;
    for (int c = 0; c < 128; ++c) s += ybuf[c] * w1[t * 128 + c];
    hid[t] = fmaxf(s, 0.f);
  }
  __syncthreads();
  float s = 0.f;
#pragma unroll
  for (int j = 0; j < 8; ++j) s += hid[j] * w2[t * 8 + j];
  att[b * 128 + t] = 1.f / (1.f + expf(-s));
}

// ------------------------------- SE combine: relu(a*xl_up + (1-a)*x_big)
__global__ __launch_bounds__(BLK) void se_k(const float* __restrict__ xlbt,
                                            const float* __restrict__ att,
                                            float* __restrict__ out) {
  int idx = blockIdx.x * BLK + threadIdx.x;
  int p = idx % 3136;
  int bo = idx / 3136;
  int h = p / 56, w = p % 56;
  float a = att[bo];
  float xl = xlbt[(size_t)bo * 784 + (h >> 1) * 28 + (w >> 1)];
  float xb = out[idx];
  out[idx] = fmaxf(a * xl + (1.f - a) * xb, 0.f);
}

// ---------------------------------------------------------------- launcher
extern "C" void kernel_launch(void* const* d_in, const int* in_sizes, int n_in,
                              void* d_out, int out_size, void* d_ws, size_t ws_size,
                              hipStream_t stream) {
  const float* x      = (const float*)d_in[0];
  const float* gumbel = (const float*)d_in[1];
  const float* nav_w  = (const float*)d_in[2];
  const float* nbg    = (const float*)d_in[3];
  const float* nbb    = (const float*)d_in[4];
  const float* gsw    = (const float*)d_in[5];
  const float* gsb    = (const float*)d_in[6];
  const float* ba_w1  = (const float*)d_in[7];
  const float* ba_g1  = (const float*)d_in[8];
  const float* ba_b1  = (const float*)d_in[9];
  const float* ba_w2  = (const float*)d_in[10];
  const float* ba_g2  = (const float*)d_in[11];
  const float* ba_b2  = (const float*)d_in[12];
  const float* bf_wd  = (const float*)d_in[13];
  const float* bf_gd  = (const float*)d_in[14];
  const float* bf_bd  = (const float*)d_in[15];
  const float* bf_w1  = (const float*)d_in[16];
  const float* bf_g1  = (const float*)d_in[17];
  const float* bf_b1  = (const float*)d_in[18];
  const float* bf_w2  = (const float*)d_in[19];
  const float* bf_g2  = (const float*)d_in[20];
  const float* bf_b2  = (const float*)d_in[21];
  const float* bt_w   = (const float*)d_in[22];
  const float* bt_g   = (const float*)d_in[23];
  const float* bt_b   = (const float*)d_in[24];
  const float* att_w1 = (const float*)d_in[25];
  const float* att_w2 = (const float*)d_in[26];
  const float* fu_w1  = (const float*)d_in[27];
  const float* fu_g1  = (const float*)d_in[28];
  const float* fu_b1  = (const float*)d_in[29];
  const float* fu_w2  = (const float*)d_in[30];
  const float* fu_g2  = (const float*)d_in[31];
  const float* fu_b2  = (const float*)d_in[32];

  float* out = (float*)d_out;
  float* ws  = (float*)d_ws;

  const size_t N_OUT = 51380224;  // 128*128*56*56
  float* bufA = ws;               // h_f, then h_fu
  float* xlbt = bufA + N_OUT;     // [128,128,28,28]
  float* resl = xlbt + 12845056;  // res_l -> x_little
  float* ha   = resl + 6422528;   // h_a
  float* ygap = ha + 6422528;     // [128,64]
  float* mskv = ygap + 8192;      // [128]
  float* ysum = mskv + 128;       // [128,128]
  float* attb = ysum + 16384;     // [128,128]
  float* wend = attb + 16384;
  // bf16 weight packs (sizes in floats = bf16elems/2)
  __bf16* wsW1 = (__bf16*)(wend);                 // 73728 bf16  (36864 f)
  __bf16* wsW2 = (__bf16*)(wend + 36864);         // 147456 bf16 (73728 f)
  __bf16* wsF1 = (__bf16*)(wend + 110592);        // 147456 bf16
  __bf16* wsF2 = (__bf16*)(wend + 184320);        // 147456 bf16
  __bf16* wsA2 = (__bf16*)(wend + 258048);        // 36864 bf16  (18432 f)
  __bf16* wsWd = (__bf16*)(wend + 276480);        // 8192 bf16   (4096 f)
  float* mask_out = out + ((size_t)out_size - 128);

  // weight prepack (bf16 fragment layout)
  pack3_k<<<36, BLK, 0, stream>>>(bf_w1, wsW1, 64, 8);
  pack3_k<<<72, BLK, 0, stream>>>(bf_w2, wsW2, 128, 8);
  pack3_k<<<72, BLK, 0, stream>>>(fu_w1, wsF1, 128, 8);
  pack3_k<<<72, BLK, 0, stream>>>(fu_w2, wsF2, 128, 8);
  pack3_k<<<18, BLK, 0, stream>>>(ba_w2, wsA2, 64, 4);
  pack1_k<<<4, BLK, 0, stream>>>(bf_wd, wsWd, 64, 8);

  // navigation mask
  gap_x_k<<<8192, BLK, 0, stream>>>(x, ygap);
  mask_k<<<1, 128, 0, stream>>>(ygap, gumbel, nav_w, nbg, nbb, gsw, gsb, mskv, mask_out);

  // ample branch
  avgpool_k<<<25088, BLK, 0, stream>>>(x, resl);
  conv3x3_k<64, 2, 0><<<dim3(1, 8, 128), BLK, 0, stream>>>(
      x, ba_w1, ba_g1, ba_b1, nullptr, ha, 56, 56, 28, 28, 64, 784);
  conv3_mfma<28, 64, 2, 1><<<dim3(7, 128), BLK, 0, stream>>>(
      ha, wsA2, ba_g2, ba_b2, resl, resl);
  conv1x1_bt_k<<<dim3(1, 16, 128), BLK, 0, stream>>>(resl, bt_w, bt_g, bt_b, xlbt);

  // focal branch
  conv3_mfma<56, 64, 4, 0><<<dim3(25, 128), BLK, 0, stream>>>(
      x, wsW1, bf_g1, bf_b1, nullptr, bufA);
  conv_xbig_mfma<<<dim3(25, 128), BLK, 0, stream>>>(
      bufA, x, wsW2, wsWd, bf_g2, bf_b2, bf_gd, bf_bd, mskv, out);

  // SE fusion
  gap2_k<<<16384, BLK, 0, stream>>>(out, xlbt, ysum);
  att_k<<<128, 128, 0, stream>>>(ysum, att_w1, att_w2, attb);
  se_k<<<200704, BLK, 0, stream>>>(xlbt, attb, out);

  // fusion residual block
  conv3_mfma<56, 128, 4, 0><<<dim3(25, 128), BLK, 0, stream>>>(
      out, wsF1, fu_g1, fu_b1, nullptr, bufA);
  conv3_mfma<56, 128, 4, 2><<<dim3(25, 128), BLK, 0, stream>>>(
      bufA, wsF2, fu_g2, fu_b2, out, out);
}